// Round 10
// baseline (231.892 us; speedup 1.0000x reference)
//
#include <hip/hip_runtime.h>
#include <stdint.h>

#define LOG2E  1.44269504088896f
#define QSCALE (0.125f * LOG2E)   // folded into Q: sacc is already the exp2 argument

typedef float    f32x4_t  __attribute__((ext_vector_type(4)));
typedef float    f32x16_t __attribute__((ext_vector_type(16)));
typedef _Float16 f16x8_t  __attribute__((ext_vector_type(8)));
typedef _Float16 f16x2_t  __attribute__((ext_vector_type(2)));

#if __has_builtin(__builtin_amdgcn_exp2f)
#define EXP2F(x) __builtin_amdgcn_exp2f(x)
#else
#define EXP2F(x) exp2f(x)
#endif

__device__ __forceinline__ float rowsum2(f16x2_t p, float acc) {
#if __has_builtin(__builtin_amdgcn_fdot2)
  return __builtin_amdgcn_fdot2(p, (f16x2_t){(_Float16)1.0f, (_Float16)1.0f}, acc, false);
#else
  return acc + (float)p[0] + (float)p[1];
#endif
}

// packed f32x2 -> f16x2 convert (v_cvt_pkrtz_f16_f32): 1 instr replaces 2 cvt + pack
__device__ __forceinline__ f16x2_t cvt2(float a, float b) {
#if __has_builtin(__builtin_amdgcn_cvt_pkrtz)
  auto r = __builtin_amdgcn_cvt_pkrtz(a, b);
  f16x2_t o;
  __builtin_memcpy(&o, &r, sizeof(o));
  return o;
#else
  return (f16x2_t){(_Float16)a, (_Float16)b};
#endif
}

// ---------------- fused prep: mask scan + K f32->f16 + V transpose ----------------
// grid 2048 x 256. Blocks 0..2047: mask chunk + K-convert chunk. Blocks 0..1023: one V tile.
__global__ void prep_kernel(const float* __restrict__ M, const float* __restrict__ K,
                            const float* __restrict__ V, _Float16* __restrict__ Kh,
                            _Float16* __restrict__ Vth, int* __restrict__ flag) {
  __shared__ __align__(16) _Float16 T[64 * 72];
  const int tid = threadIdx.x;
  const int bid = blockIdx.x;

  // -- mask all-zero scan (67 MB total) --
  {
    const float* p = M + (size_t)bid * 8192 + (size_t)tid * 4;
    unsigned acc = 0;
#pragma unroll
    for (int i = 0; i < 8; ++i) {
      f32x4_t v = *(const f32x4_t*)(p + (size_t)i * 1024);
      acc |= __float_as_uint(v[0]) | __float_as_uint(v[1]) |
             __float_as_uint(v[2]) | __float_as_uint(v[3]);
    }
    if (acc & 0x7fffffffu) atomicOr(flag, 1);
  }

  if (Kh != nullptr) {
    // -- K f32 -> f16 (8 elems/thread) --
    {
      const size_t idx = ((size_t)bid * 256 + tid) * 8;
      f32x4_t a = *(const f32x4_t*)(K + idx);
      f32x4_t b = *(const f32x4_t*)(K + idx + 4);
      union { _Float16 h[8]; uint4 q; } U;
#pragma unroll
      for (int j = 0; j < 4; ++j) { U.h[j] = (_Float16)a[j]; U.h[4 + j] = (_Float16)b[j]; }
      *(uint4*)(Kh + idx) = U.q;
    }
    // -- V transpose to [head][feat][seq] f16, one 64x64 tile per block (blocks 0..1023) --
    if (bid < 1024) {
      const int head = bid >> 6;
      const int st   = bid & 63;
      const size_t hoff = (size_t)head * 4096 * 64;
      const int sl    = tid >> 2;
      const int fbase = (tid & 3) * 16;
      const float* src = V + hoff + (size_t)(st * 64 + sl) * 64 + fbase;
#pragma unroll
      for (int c = 0; c < 4; ++c) {
        f32x4_t a = *(const f32x4_t*)(src + c * 4);
#pragma unroll
        for (int j = 0; j < 4; ++j) T[(fbase + c * 4 + j) * 72 + sl] = (_Float16)a[j];
      }
      __syncthreads();
      const int feat = tid >> 2;
      const int sb   = (tid & 3) * 16;
      uint4 r0 = *(const uint4*)&T[feat * 72 + sb];
      uint4 r1 = *(const uint4*)&T[feat * 72 + sb + 8];
      _Float16* dst = Vth + hoff + (size_t)feat * 4096 + st * 64 + sb;
      *(uint4*)(dst)     = r0;
      *(uint4*)(dst + 8) = r1;
    }
  }
}

// ---------------- SDPA: intra-block split-K, 512 threads (r9 proven) ----------------
// Waves 0-3: K-half 0; waves 4-7: K-half 1; same 128 q-cols. Partials merge via one
// LDS round-trip over the dead staging buffers (pure add: no online-softmax state).
// r10 delta: packed cvt_pkrtz for the P f32->f16 conversion (saves ~8 VALU/a-iter).
__launch_bounds__(512, 2)
__global__ void sdpa_split(const float* __restrict__ Qg, const float* __restrict__ Mg,
                           const _Float16* __restrict__ Kh, const _Float16* __restrict__ Vth,
                           float* __restrict__ Og, const int* __restrict__ flag) {
  __shared__ __align__(16) _Float16 Ks[2][64 * 72];   // [khalf][key][feat]
  __shared__ __align__(16) _Float16 Vt[2][64 * 72];   // [khalf][feat][key]

  const int tid   = threadIdx.x;
  const int bid   = blockIdx.x;
  const int khalf = tid >> 8;         // 0: tiles 0..31, 1: tiles 32..63
  const int ht    = tid & 255;        // thread id within half
  const int hh    = ((bid & 7) << 1) | ((bid >> 3) & 1);   // 2 heads per XCD
  const int qt    = bid >> 4;
  const int w     = ht >> 6;
  const int lane  = tid & 63;
  const int n     = lane & 31;
  const int h2    = lane >> 5;
  const int sig   = (n & 0x13) | ((n >> 1) & 4) | ((n << 1) & 8);  // swap bits 2,3
  const bool has_mask = (*flag) != 0;

  const size_t hoff = (size_t)hh * 4096 * 64;
  const int qcol = qt * 128 + w * 32 + n;
  const int ktlo = khalf * 32;

  // ---- Q B-fragment straight from f32 (each half reads the same Q; L2-hit) ----
  f16x8_t qf[4];
  {
    const float* qp = Qg + hoff + (size_t)qcol * 64 + 8 * h2;
#pragma unroll
    for (int kh = 0; kh < 4; ++kh) {
      f32x4_t a = *(const f32x4_t*)(qp + kh * 16);
      f32x4_t b = *(const f32x4_t*)(qp + kh * 16 + 4);
      union { _Float16 h[8]; f16x8_t v; } U;
#pragma unroll
      for (int j = 0; j < 4; ++j) { U.h[j] = (_Float16)(a[j] * QSCALE); U.h[4 + j] = (_Float16)(b[j] * QSCALE); }
      qf[kh] = U.v;
    }
  }

  f32x16_t o0 = {0.f,0.f,0.f,0.f,0.f,0.f,0.f,0.f,0.f,0.f,0.f,0.f,0.f,0.f,0.f,0.f};
  f32x16_t o1 = o0;
  float lacc = 0.0f;

#pragma unroll 1
  for (int kk = 0; kk < 32; ++kk) {
    const int kbase = (ktlo + kk) * 64;

    // -- staging prefetch (global -> regs), r8-proven order --
    uint4 kk0, kk1, vv0, vv1;
    {
      const _Float16* kp = Kh + hoff + (size_t)(kbase + (ht >> 2)) * 64 + (ht & 3) * 16;
      kk0 = *(const uint4*)(kp);
      kk1 = *(const uint4*)(kp + 8);
      const _Float16* vp = Vth + hoff + (size_t)(ht >> 2) * 4096 + kbase + (ht & 3) * 16;
      vv0 = *(const uint4*)(vp);
      vv1 = *(const uint4*)(vp + 8);
    }

    // -- mask tile: element (kb, reg=8a+4b+c) -> key kb*32 + 16a + 8*h2 + 4b + c --
    f32x4_t mk[2][2][2];
    if (has_mask) {
      const float* mp = Mg + (size_t)qcol * 4096 + kbase + 8 * h2;
#pragma unroll
      for (int kb = 0; kb < 2; ++kb)
#pragma unroll
        for (int a = 0; a < 2; ++a)
#pragma unroll
          for (int b = 0; b < 2; ++b)
            mk[kb][a][b] = *(const f32x4_t*)(mp + kb * 32 + 16 * a + 4 * b);
    }

    __syncthreads();   // prior iteration's LDS reads complete before overwrite

    *(uint4*)&Ks[khalf][(ht >> 2) * 72 + (ht & 3) * 16]     = kk0;
    *(uint4*)&Ks[khalf][(ht >> 2) * 72 + (ht & 3) * 16 + 8] = kk1;
    *(uint4*)&Vt[khalf][(ht >> 2) * 72 + (ht & 3) * 16]     = vv0;
    *(uint4*)&Vt[khalf][(ht >> 2) * 72 + (ht & 3) * 16 + 8] = vv1;

    __syncthreads();   // staging visible to all waves

#pragma unroll
    for (int kb = 0; kb < 2; ++kb) {
      // ---- S^T = K.Q^T with sigma-permuted A rows ----
      f32x16_t acc = {0.f,0.f,0.f,0.f,0.f,0.f,0.f,0.f,0.f,0.f,0.f,0.f,0.f,0.f,0.f,0.f};
#pragma unroll
      for (int kh = 0; kh < 4; ++kh) {
        const f16x8_t ka = *(const f16x8_t*)&Ks[khalf][(kb * 32 + sig) * 72 + kh * 16 + 8 * h2];
        acc = __builtin_amdgcn_mfma_f32_32x32x16_f16(ka, qf[kh], acc, 0, 0, 0);
      }
      // ---- softmax + PV, lane-local: frag f = 2*kb + a uses regs 8a..8a+7 ----
#pragma unroll
      for (int a = 0; a < 2; ++a) {
        union { _Float16 h[8]; f16x8_t v; f16x2_t p2[4]; } F;
#pragma unroll
        for (int t = 0; t < 4; ++t) {
          float x0 = acc[8 * a + 2 * t];
          float x1 = acc[8 * a + 2 * t + 1];
          if (has_mask) {
            x0 = __builtin_fmaf(mk[kb][a][t >> 1][(2 * t) & 3],     LOG2E, x0);
            x1 = __builtin_fmaf(mk[kb][a][t >> 1][(2 * t + 1) & 3], LOG2E, x1);
          }
          F.p2[t] = cvt2(EXP2F(x0), EXP2F(x1));
          lacc = rowsum2(F.p2[t], lacc);
        }
        const int f = kb * 2 + a;
        const f16x8_t v0 = *(const f16x8_t*)&Vt[khalf][n * 72 + f * 16 + 8 * h2];
        o0 = __builtin_amdgcn_mfma_f32_32x32x16_f16(F.v, v0, o0, 0, 0, 0);
        const f16x8_t v1 = *(const f16x8_t*)&Vt[khalf][(32 + n) * 72 + f * 16 + 8 * h2];
        o1 = __builtin_amdgcn_mfma_f32_32x32x16_f16(F.v, v1, o1, 0, 0, 0);
      }
    }
  }

  // ---- merge halves via dead staging LDS (pure add: no online-softmax state) ----
  float* const Xo0 = (float*)&Ks[0][0];
  float* const Xo1 = (float*)&Vt[0][0];
  float* const Xl  = Xo0 + 4096;

  __syncthreads();   // all waves done with staging LDS
  if (khalf == 1) {
#pragma unroll
    for (int reg = 0; reg < 16; ++reg) {
      Xo0[(w * 16 + reg) * 64 + lane] = o0[reg];   // lane-contiguous: conflict-free
      Xo1[(w * 16 + reg) * 64 + lane] = o1[reg];
    }
    Xl[w * 64 + lane] = lacc;
  }
  __syncthreads();
  if (khalf == 0) {
#pragma unroll
    for (int reg = 0; reg < 16; ++reg) {
      o0[reg] += Xo0[(w * 16 + reg) * 64 + lane];
      o1[reg] += Xo1[(w * 16 + reg) * 64 + lane];
    }
    lacc += Xl[w * 64 + lane];

    float lq = lacc + __shfl_xor(lacc, 32);
    float* op = Og + hoff;
#pragma unroll
    for (int r2 = 0; r2 < 4; ++r2) {
#pragma unroll
      for (int rr = 0; rr < 4; ++rr) {
        const int reg  = r2 * 4 + rr;
        const int qrow = rr + 8 * r2 + 4 * h2;      // C/D row mapping (m74/m101)
        float lr  = __shfl(lq, qrow);
        float inv = 1.0f / lr;
        const size_t row = (size_t)(qt * 128 + w * 32 + qrow) * 64;
        op[row + n]      = o0[reg] * inv;
        op[row + 32 + n] = o1[reg] * inv;
      }
    }
  }
}

// ---------------- fallback (no workspace): r8 proven 256-thread body ----------------
__launch_bounds__(256, 2)
__global__ void sdpa_fallback(const float* __restrict__ Qg, const float* __restrict__ Kg,
                              const float* __restrict__ Vg, const float* __restrict__ Mg,
                              float* __restrict__ Og, const int* __restrict__ flag) {
  __shared__ __align__(16) _Float16 Ks[64 * 72];
  __shared__ __align__(16) _Float16 Vt[64 * 72];

  const int tid  = threadIdx.x;
  const int bid  = blockIdx.x;
  const int hh   = ((bid & 7) << 1) | ((bid >> 3) & 1);
  const int qt   = bid >> 4;
  const int w    = tid >> 6;
  const int lane = tid & 63;
  const int n    = lane & 31;
  const int h2   = lane >> 5;
  const int sig  = (n & 0x13) | ((n >> 1) & 4) | ((n << 1) & 8);
  const bool has_mask = (*flag) != 0;

  const size_t hoff = (size_t)hh * 4096 * 64;
  const int qcol = qt * 128 + w * 32 + n;

  f16x8_t qf[4];
  {
    const float* qp = Qg + hoff + (size_t)qcol * 64 + 8 * h2;
#pragma unroll
    for (int kh = 0; kh < 4; ++kh) {
      f32x4_t a = *(const f32x4_t*)(qp + kh * 16);
      f32x4_t b = *(const f32x4_t*)(qp + kh * 16 + 4);
      union { _Float16 h[8]; f16x8_t v; } U;
#pragma unroll
      for (int j = 0; j < 4; ++j) { U.h[j] = (_Float16)(a[j] * QSCALE); U.h[4 + j] = (_Float16)(b[j] * QSCALE); }
      qf[kh] = U.v;
    }
  }

  f32x16_t o0 = {0.f,0.f,0.f,0.f,0.f,0.f,0.f,0.f,0.f,0.f,0.f,0.f,0.f,0.f,0.f,0.f};
  f32x16_t o1 = o0;
  float lacc = 0.0f;

#pragma unroll 1
  for (int kt = 0; kt < 64; ++kt) {
    const int kbase = kt * 64;
    f32x4_t k0, k1, k2, k3;
    float vlo[8], vhi[8];
    {
      const float* kp = Kg + hoff + (size_t)(kbase + (tid >> 2)) * 64 + (tid & 3) * 16;
      k0 = *(const f32x4_t*)(kp + 0);
      k1 = *(const f32x4_t*)(kp + 4);
      k2 = *(const f32x4_t*)(kp + 8);
      k3 = *(const f32x4_t*)(kp + 12);
      const float* vp = Vg + hoff + (size_t)(kbase + (tid >> 5) * 8) * 64 + (tid & 31);
#pragma unroll
      for (int j = 0; j < 8; ++j) {
        vlo[j] = vp[(size_t)j * 64];
        vhi[j] = vp[(size_t)j * 64 + 32];
      }
    }
    f32x4_t mk[2][2][2];
    if (has_mask) {
      const float* mp = Mg + (size_t)qcol * 4096 + kbase + 8 * h2;
#pragma unroll
      for (int kb = 0; kb < 2; ++kb)
#pragma unroll
        for (int a = 0; a < 2; ++a)
#pragma unroll
          for (int b = 0; b < 2; ++b)
            mk[kb][a][b] = *(const f32x4_t*)(mp + kb * 32 + 16 * a + 4 * b);
    }

    __syncthreads();
    {
      union { _Float16 h[8]; uint4 q; } A, B;
#pragma unroll
      for (int j = 0; j < 4; ++j) {
        A.h[j] = (_Float16)k0[j];  A.h[4 + j] = (_Float16)k1[j];
        B.h[j] = (_Float16)k2[j];  B.h[4 + j] = (_Float16)k3[j];
      }
      *(uint4*)&Ks[(tid >> 2) * 72 + (tid & 3) * 16]     = A.q;
      *(uint4*)&Ks[(tid >> 2) * 72 + (tid & 3) * 16 + 8] = B.q;
      union { _Float16 h[8]; uint4 q; } C, D;
#pragma unroll
      for (int j = 0; j < 8; ++j) { C.h[j] = (_Float16)vlo[j]; D.h[j] = (_Float16)vhi[j]; }
      *(uint4*)&Vt[(tid & 31) * 72 + (tid >> 5) * 8]        = C.q;
      *(uint4*)&Vt[((tid & 31) + 32) * 72 + (tid >> 5) * 8] = D.q;
    }
    __syncthreads();

#pragma unroll
    for (int kb = 0; kb < 2; ++kb) {
      f32x16_t acc = {0.f,0.f,0.f,0.f,0.f,0.f,0.f,0.f,0.f,0.f,0.f,0.f,0.f,0.f,0.f,0.f};
#pragma unroll
      for (int kh = 0; kh < 4; ++kh) {
        const f16x8_t ka = *(const f16x8_t*)&Ks[(kb * 32 + sig) * 72 + kh * 16 + 8 * h2];
        acc = __builtin_amdgcn_mfma_f32_32x32x16_f16(ka, qf[kh], acc, 0, 0, 0);
      }
#pragma unroll
      for (int a = 0; a < 2; ++a) {
        union { _Float16 h[8]; f16x8_t v; f16x2_t p2[4]; } F;
#pragma unroll
        for (int t = 0; t < 4; ++t) {
          float x0 = acc[8 * a + 2 * t];
          float x1 = acc[8 * a + 2 * t + 1];
          if (has_mask) {
            x0 = __builtin_fmaf(mk[kb][a][t >> 1][(2 * t) & 3],     LOG2E, x0);
            x1 = __builtin_fmaf(mk[kb][a][t >> 1][(2 * t + 1) & 3], LOG2E, x1);
          }
          F.p2[t] = cvt2(EXP2F(x0), EXP2F(x1));
          lacc = rowsum2(F.p2[t], lacc);
        }
        const int f = kb * 2 + a;
        const f16x8_t v0 = *(const f16x8_t*)&Vt[n * 72 + f * 16 + 8 * h2];
        o0 = __builtin_amdgcn_mfma_f32_32x32x16_f16(F.v, v0, o0, 0, 0, 0);
        const f16x8_t v1 = *(const f16x8_t*)&Vt[(32 + n) * 72 + f * 16 + 8 * h2];
        o1 = __builtin_amdgcn_mfma_f32_32x32x16_f16(F.v, v1, o1, 0, 0, 0);
      }
    }
  }

  float lq = lacc + __shfl_xor(lacc, 32);
  float* op = Og + hoff;
#pragma unroll
  for (int r2 = 0; r2 < 4; ++r2) {
#pragma unroll
    for (int rr = 0; rr < 4; ++rr) {
      const int reg  = r2 * 4 + rr;
      const int qrow = rr + 8 * r2 + 4 * h2;
      float lr  = __shfl(lq, qrow);
      float inv = 1.0f / lr;
      const size_t row = (size_t)(qt * 128 + w * 32 + qrow) * 64;
      op[row + n]      = o0[reg] * inv;
      op[row + 32 + n] = o1[reg] * inv;
    }
  }
}

extern "C" void kernel_launch(void* const* d_in, const int* in_sizes, int n_in,
                              void* d_out, int out_size, void* d_ws, size_t ws_size,
                              hipStream_t stream) {
  const float* Q = (const float*)d_in[0];
  const float* K = (const float*)d_in[1];
  const float* V = (const float*)d_in[2];
  const float* M = (const float*)d_in[3];
  float* O = (float*)d_out;

  const size_t NELEM  = (size_t)16 * 4096 * 64;         // 4M per tensor
  const size_t need16 = 256 + 2 * NELEM * sizeof(_Float16);   // Kh + Vth
  int* flag = (int*)d_ws;
  const bool ws16 = (ws_size >= need16);
  _Float16* Kh  = ws16 ? (_Float16*)((char*)d_ws + 256) : nullptr;
  _Float16* Vth = ws16 ? Kh + NELEM : nullptr;

  hipMemsetAsync(flag, 0, sizeof(int), stream);
  prep_kernel<<<2048, 256, 0, stream>>>(M, K, V, Kh, Vth, flag);

  if (ws16) {
    sdpa_split<<<512, 512, 0, stream>>>(Q, M, Kh, Vth, O, flag);
  } else {
    sdpa_fallback<<<512, 256, 0, stream>>>(Q, K, V, M, O, flag);
  }
}

// Round 11
// 226.891 us; speedup vs baseline: 1.0220x; 1.0220x over previous
//
#include <hip/hip_runtime.h>
#include <stdint.h>

#define LOG2E  1.44269504088896f
#define QSCALE (0.125f * LOG2E)   // folded into Q: sacc is already the exp2 argument

typedef float    f32x4_t  __attribute__((ext_vector_type(4)));
typedef float    f32x16_t __attribute__((ext_vector_type(16)));
typedef _Float16 f16x8_t  __attribute__((ext_vector_type(8)));
typedef _Float16 f16x2_t  __attribute__((ext_vector_type(2)));

#if __has_builtin(__builtin_amdgcn_exp2f)
#define EXP2F(x) __builtin_amdgcn_exp2f(x)
#else
#define EXP2F(x) exp2f(x)
#endif

__device__ __forceinline__ float rowsum2(f16x2_t p, float acc) {
#if __has_builtin(__builtin_amdgcn_fdot2)
  return __builtin_amdgcn_fdot2(p, (f16x2_t){(_Float16)1.0f, (_Float16)1.0f}, acc, false);
#else
  return acc + (float)p[0] + (float)p[1];
#endif
}

// ---------------- fused prep: mask scan + K f32->f16 + V transpose ----------------
// grid 2048 x 256. Blocks 0..2047: mask chunk + K-convert chunk. Blocks 0..1023: one V tile.
__global__ void prep_kernel(const float* __restrict__ M, const float* __restrict__ K,
                            const float* __restrict__ V, _Float16* __restrict__ Kh,
                            _Float16* __restrict__ Vth, int* __restrict__ flag) {
  __shared__ __align__(16) _Float16 T[64 * 72];
  const int tid = threadIdx.x;
  const int bid = blockIdx.x;

  // -- mask all-zero scan (67 MB total) --
  {
    const float* p = M + (size_t)bid * 8192 + (size_t)tid * 4;
    unsigned acc = 0;
#pragma unroll
    for (int i = 0; i < 8; ++i) {
      f32x4_t v = *(const f32x4_t*)(p + (size_t)i * 1024);
      acc |= __float_as_uint(v[0]) | __float_as_uint(v[1]) |
             __float_as_uint(v[2]) | __float_as_uint(v[3]);
    }
    if (acc & 0x7fffffffu) atomicOr(flag, 1);
  }

  if (Kh != nullptr) {
    // -- K f32 -> f16 (8 elems/thread) --
    {
      const size_t idx = ((size_t)bid * 256 + tid) * 8;
      f32x4_t a = *(const f32x4_t*)(K + idx);
      f32x4_t b = *(const f32x4_t*)(K + idx + 4);
      union { _Float16 h[8]; uint4 q; } U;
#pragma unroll
      for (int j = 0; j < 4; ++j) { U.h[j] = (_Float16)a[j]; U.h[4 + j] = (_Float16)b[j]; }
      *(uint4*)(Kh + idx) = U.q;
    }
    // -- V transpose to [head][feat][seq] f16, one 64x64 tile per block (blocks 0..1023) --
    if (bid < 1024) {
      const int head = bid >> 6;
      const int st   = bid & 63;
      const size_t hoff = (size_t)head * 4096 * 64;
      const int sl    = tid >> 2;
      const int fbase = (tid & 3) * 16;
      const float* src = V + hoff + (size_t)(st * 64 + sl) * 64 + fbase;
#pragma unroll
      for (int c = 0; c < 4; ++c) {
        f32x4_t a = *(const f32x4_t*)(src + c * 4);
#pragma unroll
        for (int j = 0; j < 4; ++j) T[(fbase + c * 4 + j) * 72 + sl] = (_Float16)a[j];
      }
      __syncthreads();
      const int feat = tid >> 2;
      const int sb   = (tid & 3) * 16;
      uint4 r0 = *(const uint4*)&T[feat * 72 + sb];
      uint4 r1 = *(const uint4*)&T[feat * 72 + sb + 8];
      _Float16* dst = Vth + hoff + (size_t)feat * 4096 + st * 64 + sb;
      *(uint4*)(dst)     = r0;
      *(uint4*)(dst + 8) = r1;
    }
  }
}

// ---------------- SDPA: intra-block split-K, 512 threads (r9 proven, FINAL) ----------------
// Waves 0-3: K-half 0 into Ks[0]/Vt[0]; waves 4-7: K-half 1 into Ks[1]/Vt[1]; same
// 128 q-cols. Inner body byte-identical to the proven r8 loop (VGPR cliff: no new
// live state). Partials merge via one LDS round-trip over the dead staging buffers
// (no online softmax -> (o,l) combine is a pure add). 2 blocks/CU x 8 waves =
// 4 waves/SIMD (register-capped max), HALF the barriers per wave vs 256-thread form.
// Falsified exits (do not re-try): in-flight staging regs (spill, r3/r4/r5),
// KVB=128 (spill+conflicts, r5), LDS-free direct (latency-bound, r7),
// global split-K combine (net loss, r2/r6), cvt_pkrtz interleave (null-neg, r10).
__launch_bounds__(512, 2)
__global__ void sdpa_split(const float* __restrict__ Qg, const float* __restrict__ Mg,
                           const _Float16* __restrict__ Kh, const _Float16* __restrict__ Vth,
                           float* __restrict__ Og, const int* __restrict__ flag) {
  __shared__ __align__(16) _Float16 Ks[2][64 * 72];   // [khalf][key][feat]
  __shared__ __align__(16) _Float16 Vt[2][64 * 72];   // [khalf][feat][key]

  const int tid   = threadIdx.x;
  const int bid   = blockIdx.x;
  const int khalf = tid >> 8;         // 0: tiles 0..31, 1: tiles 32..63
  const int ht    = tid & 255;        // thread id within half
  const int hh    = ((bid & 7) << 1) | ((bid >> 3) & 1);   // 2 heads per XCD
  const int qt    = bid >> 4;
  const int w     = ht >> 6;
  const int lane  = tid & 63;
  const int n     = lane & 31;
  const int h2    = lane >> 5;
  const int sig   = (n & 0x13) | ((n >> 1) & 4) | ((n << 1) & 8);  // swap bits 2,3
  const bool has_mask = (*flag) != 0;

  const size_t hoff = (size_t)hh * 4096 * 64;
  const int qcol = qt * 128 + w * 32 + n;
  const int ktlo = khalf * 32;

  // ---- Q B-fragment straight from f32 (each half reads the same Q; L2-hit) ----
  f16x8_t qf[4];
  {
    const float* qp = Qg + hoff + (size_t)qcol * 64 + 8 * h2;
#pragma unroll
    for (int kh = 0; kh < 4; ++kh) {
      f32x4_t a = *(const f32x4_t*)(qp + kh * 16);
      f32x4_t b = *(const f32x4_t*)(qp + kh * 16 + 4);
      union { _Float16 h[8]; f16x8_t v; } U;
#pragma unroll
      for (int j = 0; j < 4; ++j) { U.h[j] = (_Float16)(a[j] * QSCALE); U.h[4 + j] = (_Float16)(b[j] * QSCALE); }
      qf[kh] = U.v;
    }
  }

  f32x16_t o0 = {0.f,0.f,0.f,0.f,0.f,0.f,0.f,0.f,0.f,0.f,0.f,0.f,0.f,0.f,0.f,0.f};
  f32x16_t o1 = o0;
  float lacc = 0.0f;

#pragma unroll 1
  for (int kk = 0; kk < 32; ++kk) {
    const int kbase = (ktlo + kk) * 64;

    // -- staging prefetch (global -> regs), r8-proven order --
    uint4 kk0, kk1, vv0, vv1;
    {
      const _Float16* kp = Kh + hoff + (size_t)(kbase + (ht >> 2)) * 64 + (ht & 3) * 16;
      kk0 = *(const uint4*)(kp);
      kk1 = *(const uint4*)(kp + 8);
      const _Float16* vp = Vth + hoff + (size_t)(ht >> 2) * 4096 + kbase + (ht & 3) * 16;
      vv0 = *(const uint4*)(vp);
      vv1 = *(const uint4*)(vp + 8);
    }

    // -- mask tile: element (kb, reg=8a+4b+c) -> key kb*32 + 16a + 8*h2 + 4b + c --
    f32x4_t mk[2][2][2];
    if (has_mask) {
      const float* mp = Mg + (size_t)qcol * 4096 + kbase + 8 * h2;
#pragma unroll
      for (int kb = 0; kb < 2; ++kb)
#pragma unroll
        for (int a = 0; a < 2; ++a)
#pragma unroll
          for (int b = 0; b < 2; ++b)
            mk[kb][a][b] = *(const f32x4_t*)(mp + kb * 32 + 16 * a + 4 * b);
    }

    __syncthreads();   // prior iteration's LDS reads complete before overwrite

    *(uint4*)&Ks[khalf][(ht >> 2) * 72 + (ht & 3) * 16]     = kk0;
    *(uint4*)&Ks[khalf][(ht >> 2) * 72 + (ht & 3) * 16 + 8] = kk1;
    *(uint4*)&Vt[khalf][(ht >> 2) * 72 + (ht & 3) * 16]     = vv0;
    *(uint4*)&Vt[khalf][(ht >> 2) * 72 + (ht & 3) * 16 + 8] = vv1;

    __syncthreads();   // staging visible to all waves

#pragma unroll
    for (int kb = 0; kb < 2; ++kb) {
      // ---- S^T = K.Q^T with sigma-permuted A rows ----
      f32x16_t acc = {0.f,0.f,0.f,0.f,0.f,0.f,0.f,0.f,0.f,0.f,0.f,0.f,0.f,0.f,0.f,0.f};
#pragma unroll
      for (int kh = 0; kh < 4; ++kh) {
        const f16x8_t ka = *(const f16x8_t*)&Ks[khalf][(kb * 32 + sig) * 72 + kh * 16 + 8 * h2];
        acc = __builtin_amdgcn_mfma_f32_32x32x16_f16(ka, qf[kh], acc, 0, 0, 0);
      }
      // ---- softmax + PV, lane-local: frag f = 2*kb + a uses regs 8a..8a+7 ----
#pragma unroll
      for (int a = 0; a < 2; ++a) {
        union { _Float16 h[8]; f16x8_t v; f16x2_t p2[4]; } F;
#pragma unroll
        for (int idx = 0; idx < 8; ++idx) {
          float x = acc[8 * a + idx];
          if (has_mask) x = __builtin_fmaf(mk[kb][a][idx >> 2][idx & 3], LOG2E, x);
          F.h[idx] = (_Float16)EXP2F(x);
        }
#pragma unroll
        for (int t = 0; t < 4; ++t) lacc = rowsum2(F.p2[t], lacc);
        const int f = kb * 2 + a;
        const f16x8_t v0 = *(const f16x8_t*)&Vt[khalf][n * 72 + f * 16 + 8 * h2];
        o0 = __builtin_amdgcn_mfma_f32_32x32x16_f16(F.v, v0, o0, 0, 0, 0);
        const f16x8_t v1 = *(const f16x8_t*)&Vt[khalf][(32 + n) * 72 + f * 16 + 8 * h2];
        o1 = __builtin_amdgcn_mfma_f32_32x32x16_f16(F.v, v1, o1, 0, 0, 0);
      }
    }
  }

  // ---- merge halves via dead staging LDS (pure add: no online-softmax state) ----
  float* const Xo0 = (float*)&Ks[0][0];
  float* const Xo1 = (float*)&Vt[0][0];
  float* const Xl  = Xo0 + 4096;

  __syncthreads();   // all waves done with staging LDS
  if (khalf == 1) {
#pragma unroll
    for (int reg = 0; reg < 16; ++reg) {
      Xo0[(w * 16 + reg) * 64 + lane] = o0[reg];   // lane-contiguous: conflict-free
      Xo1[(w * 16 + reg) * 64 + lane] = o1[reg];
    }
    Xl[w * 64 + lane] = lacc;
  }
  __syncthreads();
  if (khalf == 0) {
#pragma unroll
    for (int reg = 0; reg < 16; ++reg) {
      o0[reg] += Xo0[(w * 16 + reg) * 64 + lane];
      o1[reg] += Xo1[(w * 16 + reg) * 64 + lane];
    }
    lacc += Xl[w * 64 + lane];

    float lq = lacc + __shfl_xor(lacc, 32);
    float* op = Og + hoff;
#pragma unroll
    for (int r2 = 0; r2 < 4; ++r2) {
#pragma unroll
      for (int rr = 0; rr < 4; ++rr) {
        const int reg  = r2 * 4 + rr;
        const int qrow = rr + 8 * r2 + 4 * h2;      // C/D row mapping (m74/m101)
        float lr  = __shfl(lq, qrow);
        float inv = 1.0f / lr;
        const size_t row = (size_t)(qt * 128 + w * 32 + qrow) * 64;
        op[row + n]      = o0[reg] * inv;
        op[row + 32 + n] = o1[reg] * inv;
      }
    }
  }
}

// ---------------- fallback (no workspace): r8 proven 256-thread body ----------------
__launch_bounds__(256, 2)
__global__ void sdpa_fallback(const float* __restrict__ Qg, const float* __restrict__ Kg,
                              const float* __restrict__ Vg, const float* __restrict__ Mg,
                              float* __restrict__ Og, const int* __restrict__ flag) {
  __shared__ __align__(16) _Float16 Ks[64 * 72];
  __shared__ __align__(16) _Float16 Vt[64 * 72];

  const int tid  = threadIdx.x;
  const int bid  = blockIdx.x;
  const int hh   = ((bid & 7) << 1) | ((bid >> 3) & 1);
  const int qt   = bid >> 4;
  const int w    = tid >> 6;
  const int lane = tid & 63;
  const int n    = lane & 31;
  const int h2   = lane >> 5;
  const int sig  = (n & 0x13) | ((n >> 1) & 4) | ((n << 1) & 8);
  const bool has_mask = (*flag) != 0;

  const size_t hoff = (size_t)hh * 4096 * 64;
  const int qcol = qt * 128 + w * 32 + n;

  f16x8_t qf[4];
  {
    const float* qp = Qg + hoff + (size_t)qcol * 64 + 8 * h2;
#pragma unroll
    for (int kh = 0; kh < 4; ++kh) {
      f32x4_t a = *(const f32x4_t*)(qp + kh * 16);
      f32x4_t b = *(const f32x4_t*)(qp + kh * 16 + 4);
      union { _Float16 h[8]; f16x8_t v; } U;
#pragma unroll
      for (int j = 0; j < 4; ++j) { U.h[j] = (_Float16)(a[j] * QSCALE); U.h[4 + j] = (_Float16)(b[j] * QSCALE); }
      qf[kh] = U.v;
    }
  }

  f32x16_t o0 = {0.f,0.f,0.f,0.f,0.f,0.f,0.f,0.f,0.f,0.f,0.f,0.f,0.f,0.f,0.f,0.f};
  f32x16_t o1 = o0;
  float lacc = 0.0f;

#pragma unroll 1
  for (int kt = 0; kt < 64; ++kt) {
    const int kbase = kt * 64;
    f32x4_t k0, k1, k2, k3;
    float vlo[8], vhi[8];
    {
      const float* kp = Kg + hoff + (size_t)(kbase + (tid >> 2)) * 64 + (tid & 3) * 16;
      k0 = *(const f32x4_t*)(kp + 0);
      k1 = *(const f32x4_t*)(kp + 4);
      k2 = *(const f32x4_t*)(kp + 8);
      k3 = *(const f32x4_t*)(kp + 12);
      const float* vp = Vg + hoff + (size_t)(kbase + (tid >> 5) * 8) * 64 + (tid & 31);
#pragma unroll
      for (int j = 0; j < 8; ++j) {
        vlo[j] = vp[(size_t)j * 64];
        vhi[j] = vp[(size_t)j * 64 + 32];
      }
    }
    f32x4_t mk[2][2][2];
    if (has_mask) {
      const float* mp = Mg + (size_t)qcol * 4096 + kbase + 8 * h2;
#pragma unroll
      for (int kb = 0; kb < 2; ++kb)
#pragma unroll
        for (int a = 0; a < 2; ++a)
#pragma unroll
          for (int b = 0; b < 2; ++b)
            mk[kb][a][b] = *(const f32x4_t*)(mp + kb * 32 + 16 * a + 4 * b);
    }

    __syncthreads();
    {
      union { _Float16 h[8]; uint4 q; } A, B;
#pragma unroll
      for (int j = 0; j < 4; ++j) {
        A.h[j] = (_Float16)k0[j];  A.h[4 + j] = (_Float16)k1[j];
        B.h[j] = (_Float16)k2[j];  B.h[4 + j] = (_Float16)k3[j];
      }
      *(uint4*)&Ks[(tid >> 2) * 72 + (tid & 3) * 16]     = A.q;
      *(uint4*)&Ks[(tid >> 2) * 72 + (tid & 3) * 16 + 8] = B.q;
      union { _Float16 h[8]; uint4 q; } C, D;
#pragma unroll
      for (int j = 0; j < 8; ++j) { C.h[j] = (_Float16)vlo[j]; D.h[j] = (_Float16)vhi[j]; }
      *(uint4*)&Vt[(tid & 31) * 72 + (tid >> 5) * 8]        = C.q;
      *(uint4*)&Vt[((tid & 31) + 32) * 72 + (tid >> 5) * 8] = D.q;
    }
    __syncthreads();

#pragma unroll
    for (int kb = 0; kb < 2; ++kb) {
      f32x16_t acc = {0.f,0.f,0.f,0.f,0.f,0.f,0.f,0.f,0.f,0.f,0.f,0.f,0.f,0.f,0.f,0.f};
#pragma unroll
      for (int kh = 0; kh < 4; ++kh) {
        const f16x8_t ka = *(const f16x8_t*)&Ks[(kb * 32 + sig) * 72 + kh * 16 + 8 * h2];
        acc = __builtin_amdgcn_mfma_f32_32x32x16_f16(ka, qf[kh], acc, 0, 0, 0);
      }
#pragma unroll
      for (int a = 0; a < 2; ++a) {
        union { _Float16 h[8]; f16x8_t v; f16x2_t p2[4]; } F;
#pragma unroll
        for (int idx = 0; idx < 8; ++idx) {
          float x = acc[8 * a + idx];
          if (has_mask) x = __builtin_fmaf(mk[kb][a][idx >> 2][idx & 3], LOG2E, x);
          F.h[idx] = (_Float16)EXP2F(x);
        }
#pragma unroll
        for (int t = 0; t < 4; ++t) lacc = rowsum2(F.p2[t], lacc);
        const int f = kb * 2 + a;
        const f16x8_t v0 = *(const f16x8_t*)&Vt[n * 72 + f * 16 + 8 * h2];
        o0 = __builtin_amdgcn_mfma_f32_32x32x16_f16(F.v, v0, o0, 0, 0, 0);
        const f16x8_t v1 = *(const f16x8_t*)&Vt[(32 + n) * 72 + f * 16 + 8 * h2];
        o1 = __builtin_amdgcn_mfma_f32_32x32x16_f16(F.v, v1, o1, 0, 0, 0);
      }
    }
  }

  float lq = lacc + __shfl_xor(lacc, 32);
  float* op = Og + hoff;
#pragma unroll
  for (int r2 = 0; r2 < 4; ++r2) {
#pragma unroll
    for (int rr = 0; rr < 4; ++rr) {
      const int reg  = r2 * 4 + rr;
      const int qrow = rr + 8 * r2 + 4 * h2;
      float lr  = __shfl(lq, qrow);
      float inv = 1.0f / lr;
      const size_t row = (size_t)(qt * 128 + w * 32 + qrow) * 64;
      op[row + n]      = o0[reg] * inv;
      op[row + 32 + n] = o1[reg] * inv;
    }
  }
}

extern "C" void kernel_launch(void* const* d_in, const int* in_sizes, int n_in,
                              void* d_out, int out_size, void* d_ws, size_t ws_size,
                              hipStream_t stream) {
  const float* Q = (const float*)d_in[0];
  const float* K = (const float*)d_in[1];
  const float* V = (const float*)d_in[2];
  const float* M = (const float*)d_in[3];
  float* O = (float*)d_out;

  const size_t NELEM  = (size_t)16 * 4096 * 64;         // 4M per tensor
  const size_t need16 = 256 + 2 * NELEM * sizeof(_Float16);   // Kh + Vth
  int* flag = (int*)d_ws;
  const bool ws16 = (ws_size >= need16);
  _Float16* Kh  = ws16 ? (_Float16*)((char*)d_ws + 256) : nullptr;
  _Float16* Vth = ws16 ? Kh + NELEM : nullptr;

  hipMemsetAsync(flag, 0, sizeof(int), stream);
  prep_kernel<<<2048, 256, 0, stream>>>(M, K, V, Kh, Vth, flag);

  if (ws16) {
    sdpa_split<<<512, 512, 0, stream>>>(Q, M, Kh, Vth, O, flag);
  } else {
    sdpa_fallback<<<512, 256, 0, stream>>>(Q, K, V, M, O, flag);
  }
}